// Round 5
// baseline (430.400 us; speedup 1.0000x reference)
//
#include <hip/hip_runtime.h>
#include <cstdint>
#include <cstddef>

// PositionalEncoderGrid: Instant-NGP multiresolution hash grid.
// B=524288 points, L=16 levels, T=2^19 entries/level, F=2 floats.
//
// R12: ONE fused kernel, direct output, no workspace.
//      Key evidence from R7/R8/R10/R11: gather service rate is ~3.0 cyc per
//      ACTIVE-LANE request, INVARIANT to L2 hit rate (R7 FETCH=297MB and
//      R8 FETCH=129MB ran at identical rates). L2 table pinning never
//      affected time -- so the whole multi-pass + ws + transpose apparatus
//      (≈123us of non-gather time) protects a constraint that doesn't bind.
//      New structure: each thread = one point, loops all 16 levels with the
//      verified x-pair gather body (6 req/pt/level), packs level pairs into
//      float4, stores out[p][..] directly (plain stores -> L2 write-combine
//      per 128B point-line). Zero auxiliary traffic, zero extra dispatches.
//      Model: ~107 active-lane req/pt * 3.0cyc / 256CU / 2.4GHz ~ 275us.

#define NUM_LEVELS 16
#define TBL_MASK ((1u << 19) - 1u)
#define PRIME_Y 2654435761u
#define PRIME_Z 805459861u
#define BATCH 524288

typedef float nfloat4 __attribute__((ext_vector_type(4)));
typedef double ndouble2 __attribute__((ext_vector_type(2)));

__constant__ float c_ns[NUM_LEVELS] = {
    16.f, 20.f, 25.f, 32.f, 40.f, 50.f, 64.f, 80.f,
    101.f, 128.f, 161.f, 203.f, 256.f, 322.f, 406.f, 512.f
};

__device__ __forceinline__ float2 d2f2(double d) {
    union { double d; float2 f; } u;
    u.d = d;
    return u.f;
}

// One level's trilinear hash-grid lookup for one point (verified R10 body).
// x-pair trick: corners (x0,c) and (x1,c) satisfy i_x1 == i_x0 ^ 1 when px
// is even (px+1 flips only bit 0; XOR with hash and pow2 mask commute on
// bit 0), and {i&~1, i|1} is one aligned 16B pair -> one dwordx4 covers
// both corners. Odd-px lanes issue 4 extra exec-masked gathers.
// Active-lane requests per point: 4 + 4*P(odd) = 6 expected.
__device__ __forceinline__ float2 level_eval(
    int l, float xs, float ys, float zs,
    const double* __restrict__ table_d)
{
    const float n = c_ns[l];
    const float tx = xs * n, ty = ys * n, tz = zs * n;
    const float fpx = floorf(tx), fpy = floorf(ty), fpz = floorf(tz);
    const float wx1 = tx - fpx, wy1 = ty - fpy, wz1 = tz - fpz;
    const uint32_t px = (uint32_t)fpx;
    const uint32_t py = (uint32_t)fpy;
    const uint32_t pz = (uint32_t)fpz;

    const uint32_t hy0 = py * PRIME_Y, hy1 = hy0 + PRIME_Y;
    const uint32_t hz0 = pz * PRIME_Z, hz1 = hz0 + PRIME_Z;
    const uint32_t b0 = hy0 ^ hz0, b1 = hy0 ^ hz1;
    const uint32_t b2 = hy1 ^ hz0, b3 = hy1 ^ hz1;

    const uint32_t i00 = (px ^ b0) & TBL_MASK;
    const uint32_t i01 = (px ^ b1) & TBL_MASK;
    const uint32_t i02 = (px ^ b2) & TBL_MASK;
    const uint32_t i03 = (px ^ b3) & TBL_MASK;
    const uint32_t qx = px + 1u;
    const uint32_t i40 = (qx ^ b0) & TBL_MASK;
    const uint32_t i41 = (qx ^ b1) & TBL_MASK;
    const uint32_t i42 = (qx ^ b2) & TBL_MASK;
    const uint32_t i43 = (qx ^ b3) & TBL_MASK;

    const double* __restrict__ tb = table_d + ((size_t)l << 19);
    const ndouble2* __restrict__ tb2 = (const ndouble2*)tb;

    const ndouble2 q0 = tb2[i00 >> 1];
    const ndouble2 q1 = tb2[i01 >> 1];
    const ndouble2 q2 = tb2[i02 >> 1];
    const ndouble2 q3 = tb2[i03 >> 1];

    const bool odd = (px & 1u) != 0u;
    double g0 = 0.0, g1 = 0.0, g2 = 0.0, g3 = 0.0;
    if (odd) {   // exec-masked: only odd-px lanes issue these 4 gathers
        g0 = tb[i40];
        g1 = tb[i41];
        g2 = tb[i42];
        g3 = tb[i43];
    }

    const double e00 = (i00 & 1u) ? q0.y : q0.x;
    const double e01 = (i01 & 1u) ? q1.y : q1.x;
    const double e02 = (i02 & 1u) ? q2.y : q2.x;
    const double e03 = (i03 & 1u) ? q3.y : q3.x;
    const double p00 = (i00 & 1u) ? q0.x : q0.y;
    const double p01 = (i01 & 1u) ? q1.x : q1.y;
    const double p02 = (i02 & 1u) ? q2.x : q2.y;
    const double p03 = (i03 & 1u) ? q3.x : q3.y;

    float2 f[8];
    f[0] = d2f2(e00); f[1] = d2f2(e01); f[2] = d2f2(e02); f[3] = d2f2(e03);
    f[4] = d2f2(odd ? g0 : p00);
    f[5] = d2f2(odd ? g1 : p01);
    f[6] = d2f2(odd ? g2 : p02);
    f[7] = d2f2(odd ? g3 : p03);

    const float wx0 = 1.0f - wx1;
    const float wy0 = 1.0f - wy1;
    const float wz0 = 1.0f - wz1;

    float a0 = 0.0f, a1 = 0.0f, w;
    w = wx0 * wy0 * wz0; a0 = fmaf(f[0].x, w, a0); a1 = fmaf(f[0].y, w, a1);
    w = wx0 * wy0 * wz1; a0 = fmaf(f[1].x, w, a0); a1 = fmaf(f[1].y, w, a1);
    w = wx0 * wy1 * wz0; a0 = fmaf(f[2].x, w, a0); a1 = fmaf(f[2].y, w, a1);
    w = wx0 * wy1 * wz1; a0 = fmaf(f[3].x, w, a0); a1 = fmaf(f[3].y, w, a1);
    w = wx1 * wy0 * wz0; a0 = fmaf(f[4].x, w, a0); a1 = fmaf(f[4].y, w, a1);
    w = wx1 * wy0 * wz1; a0 = fmaf(f[5].x, w, a0); a1 = fmaf(f[5].y, w, a1);
    w = wx1 * wy1 * wz0; a0 = fmaf(f[6].x, w, a0); a1 = fmaf(f[6].y, w, a1);
    w = wx1 * wy1 * wz1; a0 = fmaf(f[7].x, w, a0); a1 = fmaf(f[7].y, w, a1);
    return make_float2(a0, a1);
}

// Fused: one thread = one point, all 16 levels, direct [B,L*F] output.
__global__ __launch_bounds__(256) void enc_fused_kernel(
    const float* __restrict__ in,
    const float* __restrict__ table,
    nfloat4* __restrict__ out)         // [B*8] float4
{
    const int p = blockIdx.x * 256 + threadIdx.x;

    const float vx = __builtin_nontemporal_load(&in[p * 3 + 0]);
    const float vy = __builtin_nontemporal_load(&in[p * 3 + 1]);
    const float vz = __builtin_nontemporal_load(&in[p * 3 + 2]);
    const float xs = (vx + 3.0f) / 6.0f;
    const float ys = (vy + 3.0f) / 6.0f;
    const float zs = (vz + 3.0f) / 6.0f;

    const double* __restrict__ table_d = (const double*)table;
    nfloat4* __restrict__ op = out + (size_t)p * 8;

    // Level pairs: two evals -> one float4 store. Scalar temps only (no
    // runtime-indexed register arrays -> no scratch). unroll 1 pins VGPR.
#pragma unroll 1
    for (int lp = 0; lp < 8; ++lp) {
        const float2 r0 = level_eval(2 * lp + 0, xs, ys, zs, table_d);
        const float2 r1 = level_eval(2 * lp + 1, xs, ys, zs, table_d);
        nfloat4 r;
        r.x = r0.x; r.y = r0.y; r.z = r1.x; r.w = r1.y;
        op[lp] = r;   // plain store: 8 writes/128B point-line combine in L2
    }
}

extern "C" void kernel_launch(void* const* d_in, const int* in_sizes, int n_in,
                              void* d_out, int out_size, void* d_ws, size_t ws_size,
                              hipStream_t stream) {
    const float* inputs = (const float*)d_in[0];   // [B,3] fp32
    const float* table  = (const float*)d_in[1];   // [16, 2^19, 2] fp32

    // Single dispatch: 524288/256 = 2048 blocks.
    enc_fused_kernel<<<2048, 256, 0, stream>>>(inputs, table, (nfloat4*)d_out);
}

// Round 6
// 341.596 us; speedup vs baseline: 1.2600x; 1.2600x over previous
//
#include <hip/hip_runtime.h>
#include <cstdint>
#include <cstddef>

// PositionalEncoderGrid: Instant-NGP multiresolution hash grid.
// B=524288 points, L=16 levels, T=2^19 entries/level, F=2 floats.
//
// R13: R11's verified pass structure (pass1 l8-15 one-level-per-XCD,
//      pass2 l2-7 fractional, chunk-major ws) with coarse l0/l1 FUSED into
//      the transpose kernel: each transpose thread owns one point, computes
//      l0/l1 inline (12 active-lane req/pt; tables 0.3+0.6 MB -> L2-resident
//      on every XCD) while streaming l2-15 from ws. Deletes the coarse
//      dispatch (22us serial) and 2 levels of ws traffic; fused transpose
//      is TA(31us)+stream(24us) partially overlapped -> ~35-45us vs 48.
//      Evidence recap: gather service ~3.0cyc/active-lane-request, invariant
//      to L2 residency up to ~2 tables/XCD (R7) but +43% when fully
//      unpinned (R12, FETCH 949MB); fixed harness overhead ~72us.

#define NUM_LEVELS 16
#define TBL_MASK ((1u << 19) - 1u)
#define PRIME_Y 2654435761u
#define PRIME_Z 805459861u
#define BATCH 524288

typedef float nfloat4 __attribute__((ext_vector_type(4)));
typedef double ndouble2 __attribute__((ext_vector_type(2)));

__constant__ float c_ns[NUM_LEVELS] = {
    16.f, 20.f, 25.f, 32.f, 40.f, 50.f, 64.f, 80.f,
    101.f, 128.f, 161.f, 203.f, 256.f, 322.f, 406.f, 512.f
};

__device__ __forceinline__ float2 d2f2(double d) {
    union { double d; float2 f; } u;
    u.d = d;
    return u.f;
}

__device__ __forceinline__ double f22d(float2 f) {
    union { double d; float2 f; } u;
    u.f = f;
    return u.d;
}

// chunk-major ws index (float2/double units): [p>>8][l][p&255]
__device__ __forceinline__ size_t ws_idx(int p, int l) {
    return ((size_t)(p >> 8) * NUM_LEVELS + l) * 256 + (p & 255);
}

// One level's trilinear hash-grid lookup for one point (verified R10/R12).
// x-pair trick: corners (x0,c),(x1,c) satisfy i_x1 == i_x0 ^ 1 when px even;
// {i&~1, i|1} is one aligned 16B pair -> one dwordx4 covers both corners.
// Odd-px lanes issue 4 extra exec-masked gathers. Avg 6 req/pt/level.
__device__ __forceinline__ float2 level_eval(
    int l, float xs, float ys, float zs,
    const double* __restrict__ table_d)
{
    const float n = c_ns[l];
    const float tx = xs * n, ty = ys * n, tz = zs * n;
    const float fpx = floorf(tx), fpy = floorf(ty), fpz = floorf(tz);
    const float wx1 = tx - fpx, wy1 = ty - fpy, wz1 = tz - fpz;
    const uint32_t px = (uint32_t)fpx;
    const uint32_t py = (uint32_t)fpy;
    const uint32_t pz = (uint32_t)fpz;

    const uint32_t hy0 = py * PRIME_Y, hy1 = hy0 + PRIME_Y;
    const uint32_t hz0 = pz * PRIME_Z, hz1 = hz0 + PRIME_Z;
    const uint32_t b0 = hy0 ^ hz0, b1 = hy0 ^ hz1;
    const uint32_t b2 = hy1 ^ hz0, b3 = hy1 ^ hz1;

    const uint32_t i00 = (px ^ b0) & TBL_MASK;
    const uint32_t i01 = (px ^ b1) & TBL_MASK;
    const uint32_t i02 = (px ^ b2) & TBL_MASK;
    const uint32_t i03 = (px ^ b3) & TBL_MASK;
    const uint32_t qx = px + 1u;
    const uint32_t i40 = (qx ^ b0) & TBL_MASK;
    const uint32_t i41 = (qx ^ b1) & TBL_MASK;
    const uint32_t i42 = (qx ^ b2) & TBL_MASK;
    const uint32_t i43 = (qx ^ b3) & TBL_MASK;

    const double* __restrict__ tb = table_d + ((size_t)l << 19);
    const ndouble2* __restrict__ tb2 = (const ndouble2*)tb;

    const ndouble2 q0 = tb2[i00 >> 1];
    const ndouble2 q1 = tb2[i01 >> 1];
    const ndouble2 q2 = tb2[i02 >> 1];
    const ndouble2 q3 = tb2[i03 >> 1];

    const bool odd = (px & 1u) != 0u;
    double g0 = 0.0, g1 = 0.0, g2 = 0.0, g3 = 0.0;
    if (odd) {   // exec-masked: only odd-px lanes issue these 4 gathers
        g0 = tb[i40];
        g1 = tb[i41];
        g2 = tb[i42];
        g3 = tb[i43];
    }

    const double e00 = (i00 & 1u) ? q0.y : q0.x;
    const double e01 = (i01 & 1u) ? q1.y : q1.x;
    const double e02 = (i02 & 1u) ? q2.y : q2.x;
    const double e03 = (i03 & 1u) ? q3.y : q3.x;
    const double p00 = (i00 & 1u) ? q0.x : q0.y;
    const double p01 = (i01 & 1u) ? q1.x : q1.y;
    const double p02 = (i02 & 1u) ? q2.x : q2.y;
    const double p03 = (i03 & 1u) ? q3.x : q3.y;

    float2 f[8];
    f[0] = d2f2(e00); f[1] = d2f2(e01); f[2] = d2f2(e02); f[3] = d2f2(e03);
    f[4] = d2f2(odd ? g0 : p00);
    f[5] = d2f2(odd ? g1 : p01);
    f[6] = d2f2(odd ? g2 : p02);
    f[7] = d2f2(odd ? g3 : p03);

    const float wx0 = 1.0f - wx1;
    const float wy0 = 1.0f - wy1;
    const float wz0 = 1.0f - wz1;

    float a0 = 0.0f, a1 = 0.0f, w;
    w = wx0 * wy0 * wz0; a0 = fmaf(f[0].x, w, a0); a1 = fmaf(f[0].y, w, a1);
    w = wx0 * wy0 * wz1; a0 = fmaf(f[1].x, w, a0); a1 = fmaf(f[1].y, w, a1);
    w = wx0 * wy1 * wz0; a0 = fmaf(f[2].x, w, a0); a1 = fmaf(f[2].y, w, a1);
    w = wx0 * wy1 * wz1; a0 = fmaf(f[3].x, w, a0); a1 = fmaf(f[3].y, w, a1);
    w = wx1 * wy0 * wz0; a0 = fmaf(f[4].x, w, a0); a1 = fmaf(f[4].y, w, a1);
    w = wx1 * wy0 * wz1; a0 = fmaf(f[5].x, w, a0); a1 = fmaf(f[5].y, w, a1);
    w = wx1 * wy1 * wz0; a0 = fmaf(f[6].x, w, a0); a1 = fmaf(f[6].y, w, a1);
    w = wx1 * wy1 * wz1; a0 = fmaf(f[7].x, w, a0); a1 = fmaf(f[7].y, w, a1);
    return make_float2(a0, a1);
}

// Phase A fine levels: level-major contiguous static schedule per XCD.
// g = slot*cps + seq; level = base + g/2048; chunk-in-level = g%2048.
// Per XCD, seq increases with launch order -> <=2 tables, sequential.
// (Verified R11 kernel, byte-identical math: pass1 131us, pass2 98us.)
__global__ __launch_bounds__(256) void enc_sched_kernel(
    const float* __restrict__ in,
    const float* __restrict__ table,
    double* __restrict__ ws,
    int base_level, int cps)
{
    const int slot = blockIdx.x & 7;           // -> XCD
    const int seq  = blockIdx.x >> 3;
    const int g = slot * cps + seq;
    const int l = base_level + (g >> 11);      // 2048 chunks per level
    const int cil = g & 2047;
    const int p = cil * 256 + threadIdx.x;

    // Streaming input: nt so it doesn't evict the L2-resident table.
    const float vx = __builtin_nontemporal_load(&in[p * 3 + 0]);
    const float vy = __builtin_nontemporal_load(&in[p * 3 + 1]);
    const float vz = __builtin_nontemporal_load(&in[p * 3 + 2]);
    const float xs = (vx + 3.0f) / 6.0f;
    const float ys = (vy + 3.0f) / 6.0f;
    const float zs = (vz + 3.0f) / 6.0f;

    const float2 r = level_eval(l, xs, ys, zs, (const double*)table);

    __builtin_nontemporal_store(f22d(r), &ws[ws_idx(p, l)]);
}

// Phase B fused: per-chunk transpose of l2..15 from ws + INLINE l0/l1 eval.
// Thread tid owns point p0+tid: computes l0,l1 (12 req/pt, tables L2-hot on
// every XCD), stages l2..15 from chunk-major ws, then 256x128B coalesced
// output writes.
__global__ __launch_bounds__(256) void transpose_coarse_kernel(
    const float* __restrict__ in,
    const double* __restrict__ ws,
    const float* __restrict__ table,
    nfloat4* __restrict__ out)                 // [B*8]
{
    __shared__ double lds[256][NUM_LEVELS + 1];   // +1 pad

    const int tid = threadIdx.x;
    const int p = blockIdx.x * 256 + tid;
    const size_t base = (size_t)blockIdx.x * (NUM_LEVELS * 256);

    // Stage fine levels from ws (contiguous 2KB per level slot).
#pragma unroll
    for (int l = 2; l < NUM_LEVELS; ++l) {
        lds[tid][l] = __builtin_nontemporal_load(&ws[base + (size_t)l * 256 + tid]);
    }

    // Inline coarse levels: coalesced coord load, cached table gathers.
    const float vx = in[p * 3 + 0];
    const float vy = in[p * 3 + 1];
    const float vz = in[p * 3 + 2];
    const float xs = (vx + 3.0f) / 6.0f;
    const float ys = (vy + 3.0f) / 6.0f;
    const float zs = (vz + 3.0f) / 6.0f;
    const double* __restrict__ table_d = (const double*)table;
    lds[tid][0] = f22d(level_eval(0, xs, ys, zs, table_d));
    lds[tid][1] = f22d(level_eval(1, xs, ys, zs, table_d));

    __syncthreads();

    // 2048 float4s per block; lane-contiguous stores.
#pragma unroll
    for (int it = 0; it < 8; ++it) {
        const int e = it * 256 + tid;
        const int pp = e >> 3;         // point within tile
        const int j = e & 7;           // float4 index within point
        const float2 a = d2f2(lds[pp][2 * j]);
        const float2 b = d2f2(lds[pp][2 * j + 1]);
        nfloat4 r;
        r.x = a.x; r.y = a.y; r.z = b.x; r.w = b.y;
        __builtin_nontemporal_store(r, &out[(size_t)blockIdx.x * 2048 + e]);
    }
}

// Fallback: direct scatter store (no workspace needed).
__global__ __launch_bounds__(256) void enc_scatter_kernel(
    const float* __restrict__ in,
    const float* __restrict__ table,
    float2* __restrict__ out)          // [B, 16] float2
{
    const int v = blockIdx.x & 15;
    const int chunk = blockIdx.x >> 4;
    const int l = (v < 8) ? (15 - v) : (v - 8);
    const int p = chunk * 256 + threadIdx.x;

    const float vx = in[p * 3 + 0];
    const float vy = in[p * 3 + 1];
    const float vz = in[p * 3 + 2];
    const float2 r = level_eval(l, (vx + 3.0f) / 6.0f, (vy + 3.0f) / 6.0f,
                                (vz + 3.0f) / 6.0f, (const double*)table);
    out[(size_t)p * NUM_LEVELS + l] = r;
}

extern "C" void kernel_launch(void* const* d_in, const int* in_sizes, int n_in,
                              void* d_out, int out_size, void* d_ws, size_t ws_size,
                              hipStream_t stream) {
    const float* inputs = (const float*)d_in[0];   // [B,3] fp32
    const float* table  = (const float*)d_in[1];   // [16, 2^19, 2] fp32

    const size_t ws_needed = (size_t)NUM_LEVELS * BATCH * sizeof(float2); // 64 MiB

    if (ws_size >= ws_needed) {
        double* ws = (double*)d_ws;
        // Pass 1: l8..15, one level per XCD (8 * 2048 blocks).
        enc_sched_kernel<<<16384, 256, 0, stream>>>(inputs, table, ws, 8, 2048);
        // Pass 2: l2..7 fractional over 8 XCDs (8 * 1536 blocks).
        enc_sched_kernel<<<12288, 256, 0, stream>>>(inputs, table, ws, 2, 1536);
        // Phase B: fused transpose + inline l0/l1 (2048 blocks).
        transpose_coarse_kernel<<<2048, 256, 0, stream>>>(
            inputs, ws, table, (nfloat4*)d_out);
    } else {
        enc_scatter_kernel<<<32768, 256, 0, stream>>>(inputs, table, (float2*)d_out);
    }
}